// Round 1
// baseline (76.581 us; speedup 1.0000x reference)
//
#include <hip/hip_runtime.h>

// QuantizedLinear: y[b][o] = scale * sum_k x[b][k]*(qw[o][k]-zp) + bias[o]
// M=16 (batch), K=8192 (in_f), N=8192 (out_f), all float32.
// Memory-bound on qw (256 MB, read once). Floor ~41 us @ 6.3 TB/s.

constexpr int IN_F  = 8192;
constexpr int OUT_F = 8192;
constexpr int BATCH = 16;
constexpr int ROWS_PER_WAVE = 4;   // output rows per wave (amortizes x reads 4x)
constexpr int WAVES_PER_BLOCK = 4; // 256 threads

__global__ __launch_bounds__(WAVES_PER_BLOCK * 64)
void qlinear_kernel(const float* __restrict__ x,      // [BATCH][IN_F]
                    const float* __restrict__ qw,     // [OUT_F][IN_F]
                    const float* __restrict__ scale_p,// [1]
                    const float* __restrict__ zp_p,   // [1]
                    const float* __restrict__ bias,   // [OUT_F]
                    float* __restrict__ y)            // [BATCH][OUT_F]
{
    const int lane = threadIdx.x & 63;
    const int wave = threadIdx.x >> 6;
    const int rowBase = (blockIdx.x * WAVES_PER_BLOCK + wave) * ROWS_PER_WAVE;

    const float zp = zp_p[0];
    const float scale = scale_p[0];

    float acc[BATCH][ROWS_PER_WAVE];
#pragma unroll
    for (int b = 0; b < BATCH; ++b)
#pragma unroll
        for (int r = 0; r < ROWS_PER_WAVE; ++r) acc[b][r] = 0.0f;

    // Each wave covers all of K: 64 lanes * float4 = 256 floats per iter.
    constexpr int ITERS = IN_F / 256;  // 32
    for (int it = 0; it < ITERS; ++it) {
        const int k = it * 256 + lane * 4;

        float4 w[ROWS_PER_WAVE];
#pragma unroll
        for (int r = 0; r < ROWS_PER_WAVE; ++r) {
            const float4 q = *reinterpret_cast<const float4*>(
                qw + (size_t)(rowBase + r) * IN_F + k);
            w[r].x = q.x - zp;
            w[r].y = q.y - zp;
            w[r].z = q.z - zp;
            w[r].w = q.w - zp;
        }

#pragma unroll
        for (int b = 0; b < BATCH; ++b) {
            const float4 xv = *reinterpret_cast<const float4*>(x + b * IN_F + k);
#pragma unroll
            for (int r = 0; r < ROWS_PER_WAVE; ++r) {
                acc[b][r] += xv.x * w[r].x;
                acc[b][r] += xv.y * w[r].y;
                acc[b][r] += xv.z * w[r].z;
                acc[b][r] += xv.w * w[r].w;
            }
        }
    }

    // Butterfly-reduce each of the 64 accumulators across the wave.
#pragma unroll
    for (int b = 0; b < BATCH; ++b)
#pragma unroll
        for (int r = 0; r < ROWS_PER_WAVE; ++r) {
#pragma unroll
            for (int s = 32; s >= 1; s >>= 1)
                acc[b][r] += __shfl_xor(acc[b][r], s, 64);
        }

    // Lane (b*4+r) emits acc[b][r]. Static selection (compile-time unrolled).
    float val = 0.0f;
#pragma unroll
    for (int b = 0; b < BATCH; ++b)
#pragma unroll
        for (int r = 0; r < ROWS_PER_WAVE; ++r)
            if (lane == b * ROWS_PER_WAVE + r) val = acc[b][r];

    const int b = lane >> 2;
    const int r = lane & 3;
    const int o = rowBase + r;
    y[(size_t)b * OUT_F + o] = scale * val + bias[o];
}

extern "C" void kernel_launch(void* const* d_in, const int* in_sizes, int n_in,
                              void* d_out, int out_size, void* d_ws, size_t ws_size,
                              hipStream_t stream) {
    const float* x     = (const float*)d_in[0];
    const float* qw    = (const float*)d_in[1];
    const float* scale = (const float*)d_in[2];
    const float* zp    = (const float*)d_in[3];
    const float* bias  = (const float*)d_in[4];
    float* y = (float*)d_out;

    const int rows_per_block = WAVES_PER_BLOCK * ROWS_PER_WAVE;      // 16
    const int grid = OUT_F / rows_per_block;                          // 512
    qlinear_kernel<<<grid, WAVES_PER_BLOCK * 64, 0, stream>>>(
        x, qw, scale, zp, bias, y);
}